// Round 8
// baseline (230.193 us; speedup 1.0000x reference)
//
#include <hip/hip_runtime.h>
#include <hip/hip_bf16.h>

#define BB 4096
#define DD 1024
#define NBF 16
#define HH 2048
#define KK 16384   // DD*NBF (elements; also bytes for i8 rows)
#define LN_EPS 1e-5f

typedef int   i32x4 __attribute__((ext_vector_type(4)));   // i8 MFMA A/B (16 i8) and C/D (4 i32)
typedef unsigned short us8 __attribute__((ext_vector_type(8)));

__device__ __forceinline__ unsigned short f2bf(float f) {
  union { float f; unsigned int u; } c; c.f = f;
  unsigned int u = c.u;
  return (unsigned short)((u + 0x7FFFu + ((u >> 16) & 1u)) >> 16);  // RNE
}
__device__ __forceinline__ float bf2f(unsigned short s) {
  union { unsigned int u; float f; } c; c.u = ((unsigned int)s) << 16;
  return c.f;
}
__device__ __forceinline__ float softplusf(float x) {
  return (x > 20.f) ? x : log1pf(expf(x));
}
__device__ __forceinline__ int pack4(int q0, int q1, int q2, int q3) {
  return (q0 & 0xff) | ((q1 & 0xff) << 8) | ((q2 & 0xff) << 16) | ((q3 & 0xff) << 24);
}

// cs[d*16+k] = centers[d][k] / (softplus(width[d]) + 1e-6)
__global__ void prep_kernel(const float* __restrict__ centers, const float* __restrict__ width,
                            float* __restrict__ cs) {
  const int i = blockIdx.x * 256 + threadIdx.x;  // 16384 total
  const int d = i >> 4;
  const float w = softplusf(width[d]) + 1e-6f;
  cs[i] = centers[i] / w;
}

// LayerNorm + triangular basis -> zq (i8 [B,KK], zq = round(127*phi)), and ylin[b]
__global__ __launch_bounds__(256)
void zexp_kernel(const float* __restrict__ x, const float* __restrict__ g,
                 const float* __restrict__ be, const float* __restrict__ width,
                 const float* __restrict__ sh_w, const float* __restrict__ sh_b,
                 const float* __restrict__ cs,
                 unsigned char* __restrict__ zq, float* __restrict__ ylin) {
  __shared__ float red[8];
  const int b = blockIdx.x, tid = threadIdx.x;
  const float4 v = ((const float4*)(x + (size_t)b * DD))[tid];
  float s  = v.x + v.y + v.z + v.w;
  float ss = v.x*v.x + v.y*v.y + v.z*v.z + v.w*v.w;
  #pragma unroll
  for (int off = 32; off > 0; off >>= 1) {
    s  += __shfl_xor(s, off);
    ss += __shfl_xor(ss, off);
  }
  if ((tid & 63) == 0) { red[(tid>>6)*2] = s; red[(tid>>6)*2+1] = ss; }
  __syncthreads();
  const float sum   = red[0]+red[2]+red[4]+red[6];
  const float sumsq = red[1]+red[3]+red[5]+red[7];
  const float mu   = sum * (1.f/DD);
  const float var  = sumsq * (1.f/DD) - mu*mu;
  const float rstd = rsqrtf(var + LN_EPS);
  const float4 g4 = ((const float4*)g)[tid];
  const float4 b4 = ((const float4*)be)[tid];
  const float4 w4 = ((const float4*)width)[tid];
  const float4 s4 = ((const float4*)sh_w)[tid];
  const float xn0 = (v.x - mu)*rstd*g4.x + b4.x;
  const float xn1 = (v.y - mu)*rstd*g4.y + b4.y;
  const float xn2 = (v.z - mu)*rstd*g4.z + b4.z;
  const float xn3 = (v.w - mu)*rstd*g4.w + b4.w;
  float xsv[4];
  xsv[0] = xn0 / (softplusf(w4.x) + 1e-6f);
  xsv[1] = xn1 / (softplusf(w4.y) + 1e-6f);
  xsv[2] = xn2 / (softplusf(w4.z) + 1e-6f);
  xsv[3] = xn3 / (softplusf(w4.w) + 1e-6f);
  unsigned char* zr = zq + (size_t)b * KK + tid * 64;
  #pragma unroll
  for (int j = 0; j < 4; ++j) {
    const float4* c4 = (const float4*)(cs + (tid * 4 + j) * 16);
    const float xv = xsv[j];
    int q[16];
    #pragma unroll
    for (int qq = 0; qq < 4; ++qq) {
      const float4 ca = c4[qq];
      q[qq*4+0] = __float2int_rn(fmaxf(0.f, 1.f - fabsf(xv - ca.x)) * 127.f);
      q[qq*4+1] = __float2int_rn(fmaxf(0.f, 1.f - fabsf(xv - ca.y)) * 127.f);
      q[qq*4+2] = __float2int_rn(fmaxf(0.f, 1.f - fabsf(xv - ca.z)) * 127.f);
      q[qq*4+3] = __float2int_rn(fmaxf(0.f, 1.f - fabsf(xv - ca.w)) * 127.f);
    }
    int4 o;
    o.x = pack4(q[0],  q[1],  q[2],  q[3]);
    o.y = pack4(q[4],  q[5],  q[6],  q[7]);
    o.z = pack4(q[8],  q[9],  q[10], q[11]);
    o.w = pack4(q[12], q[13], q[14], q[15]);
    ((int4*)zr)[j] = o;
  }
  float yd = xn0*s4.x + xn1*s4.y + xn2*s4.z + xn3*s4.w;
  #pragma unroll
  for (int off = 32; off > 0; off >>= 1) yd += __shfl_xor(yd, off);
  __syncthreads();
  if ((tid & 63) == 0) red[tid>>6] = yd;
  __syncthreads();
  if (tid == 0) ylin[b] = red[0]+red[1]+red[2]+red[3] + sh_b[0];
}

// fc1_w fp32 -> i8 with per-row scale. One block per row j; row held in regs.
__global__ __launch_bounds__(256)
void cvt_kernel(const float* __restrict__ w, unsigned char* __restrict__ wq,
                float* __restrict__ wscale) {
  __shared__ float red[4];
  const int j = blockIdx.x, tid = threadIdx.x;
  const float4* row4 = (const float4*)(w + (size_t)j * KK);
  float4 vv[16];
  float mx = 0.f;
  #pragma unroll
  for (int i = 0; i < 16; ++i) {
    vv[i] = row4[tid + i * 256];
    mx = fmaxf(mx, fmaxf(fmaxf(fabsf(vv[i].x), fabsf(vv[i].y)),
                         fmaxf(fabsf(vv[i].z), fabsf(vv[i].w))));
  }
  #pragma unroll
  for (int off = 32; off > 0; off >>= 1) mx = fmaxf(mx, __shfl_xor(mx, off));
  if ((tid & 63) == 0) red[tid >> 6] = mx;
  __syncthreads();
  const float smax = fmaxf(fmaxf(red[0], red[1]), fmaxf(red[2], red[3]));
  const float inv  = (smax > 0.f) ? 127.f / smax : 0.f;
  if (tid == 0) wscale[j] = smax * (1.f / 127.f);
  int* orow = (int*)(wq + (size_t)j * KK);
  #pragma unroll
  for (int i = 0; i < 16; ++i) {
    const int q0 = __float2int_rn(vv[i].x * inv);
    const int q1 = __float2int_rn(vv[i].y * inv);
    const int q2 = __float2int_rn(vv[i].z * inv);
    const int q3 = __float2int_rn(vv[i].w * inv);
    orow[tid + i * 256] = pack4(q0, q1, q2, q3);
  }
}

// h = gelu( (zq @ wq^T) * scale + fc1_b ), bf16 out.
// m201 8-phase template, i8 BK=128 (byte-identical rows to bf16 BK=64):
// BM=256 BN=128, 8 waves (4M x 2N), wave 64x64, LDS 2buf x {A 32K, B 16K} = 96 KB.
// 4 phases/K-tile x 2 tiles/iter; per phase: {ds_reads || 1 half-tile stage} ->
// s_barrier -> lgkmcnt(0) -> setprio(1) -> 8 MFMA -> setprio(0) ->
// [vmcnt(2) at ph4/ph8] -> s_barrier.  NO sched_barrier (m141 regression).
// Ledger: 8 loads max in flight; vmcnt(2) retires exactly next tile's 6 loads;
// every stage targets a region whose reads retired >=1 phase earlier.
__global__ __launch_bounds__(512, 1)
void gemm_kernel(const unsigned char* __restrict__ zq, const unsigned char* __restrict__ wq,
                 const float* __restrict__ wscale, const float* __restrict__ fc1_b,
                 unsigned short* __restrict__ h) {
  __shared__ unsigned char As[2][256 * 128];   // 64 KB
  __shared__ unsigned char Bs[2][128 * 128];   // 32 KB
  const int tid  = threadIdx.x;
  const int lane = tid & 63;
  const int wv   = tid >> 6;       // 0..7
  const int wr   = wv >> 1;        // 0..3 (M, 64 rows each)
  const int wc   = wv & 1;         // 0..1 (N, 64 cols each)
  // bijective XCD swizzle (256 % 8 == 0); bm fastest -> XCD-mates share B panel
  const int bid = (blockIdx.x & 7) * 32 + (blockIdx.x >> 3);
  const int bm = bid & 15;         // 16 M-tiles of 256
  const int bn = bid >> 4;         // 16 N-tiles of 128

  const int srow   = lane >> 3;            // row-in-8 for staging
  const int schunk = (lane & 7) ^ srow;    // pre-swizzled source 16B chunk (of 8/row)
  const int frow = lane & 15;
  const int fkb  = lane >> 4;              // 0..3

  const unsigned char* zb  = zq + (size_t)(bm * 256) * KK;
  const unsigned char* wbb = wq + (size_t)(bn * 128) * KK;

  i32x4 acc[4][4];
  #pragma unroll
  for (int m = 0; m < 4; ++m)
    #pragma unroll
    for (int n = 0; n < 4; ++n)
      acc[m][n] = (i32x4){0, 0, 0, 0};

  // one gload covers 8 rows/wave; A: j=0..3 (4 gloads = 256 rows), B: hh=0,1
  #define STAGE_A(buf, u, j) __builtin_amdgcn_global_load_lds( \
      (const __attribute__((address_space(1))) void*)(zb + (size_t)((j)*64 + wv*8 + srow) * KK + (size_t)(u)*128 + schunk*16), \
      (__attribute__((address_space(3))) void*)(&As[buf][((j)*64 + wv*8) * 128]), 16, 0, 0)
  #define STAGE_B(buf, u, hh) __builtin_amdgcn_global_load_lds( \
      (const __attribute__((address_space(1))) void*)(wbb + (size_t)((hh)*64 + wv*8 + srow) * KK + (size_t)(u)*128 + schunk*16), \
      (__attribute__((address_space(3))) void*)(&Bs[buf][((hh)*64 + wv*8) * 128]), 16, 0, 0)

  #define RD_A2(CB, dst, mbase) do { \
    _Pragma("unroll") for (int mm = 0; mm < 2; ++mm) { \
      const int Ra = wr*64 + ((mbase)+mm)*16 + frow; \
      _Pragma("unroll") for (int ks = 0; ks < 2; ++ks) { \
        const int kb = ks*4 + fkb; \
        dst[mm][ks] = *reinterpret_cast<const i32x4*>(&As[CB][Ra*128 + ((kb ^ (Ra&7))*16)]); \
      } } } while (0)
  #define RD_B2(CB, dst, nbase) do { \
    _Pragma("unroll") for (int nn = 0; nn < 2; ++nn) { \
      const int Rb = wc*64 + ((nbase)+nn)*16 + frow; \
      _Pragma("unroll") for (int ks = 0; ks < 2; ++ks) { \
        const int kb = ks*4 + fkb; \
        dst[nn][ks] = *reinterpret_cast<const i32x4*>(&Bs[CB][Rb*128 + ((kb ^ (Rb&7))*16)]); \
      } } } while (0)

  #define BAR()  asm volatile("s_barrier" ::: "memory")
  #define LGK0() asm volatile("s_waitcnt lgkmcnt(0)" ::: "memory")
  #define VM2()  asm volatile("s_waitcnt vmcnt(2)" ::: "memory")

  #define MF8(AF, BF, MO, NO) do { \
    _Pragma("unroll") for (int mm = 0; mm < 2; ++mm) \
      _Pragma("unroll") for (int nn = 0; nn < 2; ++nn) \
        _Pragma("unroll") for (int ks = 0; ks < 2; ++ks) \
          acc[(MO)+mm][(NO)+nn] = __builtin_amdgcn_mfma_i32_16x16x64_i8(AF[mm][ks], BF[nn][ks], acc[(MO)+mm][(NO)+nn], 0, 0, 0); \
  } while (0)

  // PH_GROUP: compute tile in buf CB (4 phases), staging: ph1/ph2 stage A of
  // tile uA into buf AB; ph3/ph4 stage B of tile uB into buf BBf.
  #define PH_GROUP(CB, AB, uA, BBf, uB) do { \
    i32x4 afA[2][2], afB[2][2], bf0[2][2], bf1[2][2]; \
    /* ph1 */ \
    RD_A2(CB, afA, 0); RD_B2(CB, bf0, 0); \
    STAGE_A(AB, uA, 0); STAGE_A(AB, uA, 1); \
    BAR(); LGK0(); __builtin_amdgcn_s_setprio(1); \
    MF8(afA, bf0, 0, 0); \
    __builtin_amdgcn_s_setprio(0); BAR(); \
    /* ph2 */ \
    RD_B2(CB, bf1, 2); \
    STAGE_A(AB, uA, 2); STAGE_A(AB, uA, 3); \
    BAR(); LGK0(); __builtin_amdgcn_s_setprio(1); \
    MF8(afA, bf1, 0, 2); \
    __builtin_amdgcn_s_setprio(0); BAR(); \
    /* ph3 */ \
    RD_A2(CB, afB, 2); \
    STAGE_B(BBf, uB, 0); \
    BAR(); LGK0(); __builtin_amdgcn_s_setprio(1); \
    MF8(afB, bf1, 2, 2); \
    __builtin_amdgcn_s_setprio(0); BAR(); \
    /* ph4 */ \
    STAGE_B(BBf, uB, 1); \
    BAR(); LGK0(); __builtin_amdgcn_s_setprio(1); \
    MF8(afB, bf0, 2, 0); \
    __builtin_amdgcn_s_setprio(0); \
    VM2(); BAR(); \
  } while (0)

  // ---- prologue: tile0 (B0,B1,A0-3) + tile1 (B0,B1) = 8 loads; vmcnt(2)
  //      retires the 6 oldest = tile0 fully resident ----
  STAGE_B(0, 0, 0); STAGE_B(0, 0, 1);
  STAGE_A(0, 0, 0); STAGE_A(0, 0, 1); STAGE_A(0, 0, 2); STAGE_A(0, 0, 3);
  STAGE_B(1, 1, 0); STAGE_B(1, 1, 1);
  VM2(); BAR();

  // ---- main loop: 64 iters x 2 K-tiles ----
  for (int i = 0; i < 64; ++i) {
    const int ub = 2*i + 1;                          // computed this iter (buf1)
    const int uc = (2*i + 2 < 128) ? 2*i + 2 : 127;  // next iter buf0 (clamped tail)
    const int ud = (2*i + 3 < 128) ? 2*i + 3 : 127;  // next iter buf1 (clamped tail)
    PH_GROUP(0, 1, ub, 0, uc);   // compute tile 2i   (buf0); stage b.A -> buf1, c.B -> buf0
    PH_GROUP(1, 0, uc, 1, ud);   // compute tile 2i+1 (buf1); stage c.A -> buf0, d.B -> buf1
  }
  asm volatile("s_waitcnt vmcnt(0)" ::: "memory");   // drain clamped tail stages

  // ---- epilogue: h = gelu(acc * (wscale[col]/127) + bias), bf16.
  //      C/D: col=lane&15, row=(lane>>4)*4+reg ----
  const int row0 = bm * 256 + wr * 64;
  const int col0 = bn * 128 + wc * 64;
  #pragma unroll
  for (int n = 0; n < 4; ++n) {
    const int col = col0 + n * 16 + frow;
    const float sc   = wscale[col] * (1.f / 127.f);
    const float bias = fc1_b[col];
    #pragma unroll
    for (int m = 0; m < 4; ++m) {
      #pragma unroll
      for (int r = 0; r < 4; ++r) {
        const int row = row0 + m * 16 + fkb * 4 + r;
        const float xg = (float)acc[m][n][r] * sc + bias;
        h[(size_t)row * HH + col] = f2bf(0.5f * xg * (1.f + erff(xg * 0.70710678118f)));
      }
    }
  }
  #undef STAGE_A
  #undef STAGE_B
  #undef RD_A2
  #undef RD_B2
  #undef BAR
  #undef LGK0
  #undef VM2
  #undef MF8
  #undef PH_GROUP
}

// out[b] = dot(h[b], hm_w) + hm_b + relu(gamma)*ylin[b];  out[BB+b] = dot(h[b], hv_w) + hv_b
__global__ __launch_bounds__(256)
void head_kernel(const unsigned short* __restrict__ h, const float* __restrict__ hm_w,
                 const float* __restrict__ hm_b, const float* __restrict__ hv_w,
                 const float* __restrict__ hv_b, const float* __restrict__ ylin,
                 const float* __restrict__ gamma, float* __restrict__ out) {
  __shared__ float red[8];
  const int b = blockIdx.x, tid = threadIdx.x;
  const us8 hv8 = ((const us8*)(h + (size_t)b * HH))[tid];
  const float4 m0 = ((const float4*)hm_w)[tid*2],  m1 = ((const float4*)hm_w)[tid*2+1];
  const float4 v0 = ((const float4*)hv_w)[tid*2],  v1 = ((const float4*)hv_w)[tid*2+1];
  float hf[8];
  #pragma unroll
  for (int i = 0; i < 8; ++i) hf[i] = bf2f((unsigned short)hv8[i]);
  float dm = hf[0]*m0.x + hf[1]*m0.y + hf[2]*m0.z + hf[3]*m0.w
           + hf[4]*m1.x + hf[5]*m1.y + hf[6]*m1.z + hf[7]*m1.w;
  float dv = hf[0]*v0.x + hf[1]*v0.y + hf[2]*v0.z + hf[3]*v0.w
           + hf[4]*v1.x + hf[5]*v1.y + hf[6]*v1.z + hf[7]*v1.w;
  #pragma unroll
  for (int off = 32; off > 0; off >>= 1) {
    dm += __shfl_xor(dm, off);
    dv += __shfl_xor(dv, off);
  }
  if ((tid & 63) == 0) { red[(tid>>6)*2] = dm; red[(tid>>6)*2+1] = dv; }
  __syncthreads();
  if (tid == 0) {
    const float sm = red[0]+red[2]+red[4]+red[6] + hm_b[0];
    const float sv = red[1]+red[3]+red[5]+red[7] + hv_b[0];
    out[b]      = sm + fmaxf(gamma[0], 0.f) * ylin[b];
    out[BB + b] = sv;
  }
}

extern "C" void kernel_launch(void* const* d_in, const int* in_sizes, int n_in,
                              void* d_out, int out_size, void* d_ws, size_t ws_size,
                              hipStream_t stream) {
  const float* x       = (const float*)d_in[0];
  const float* ln_g    = (const float*)d_in[1];
  const float* ln_b    = (const float*)d_in[2];
  const float* centers = (const float*)d_in[3];
  const float* width   = (const float*)d_in[4];
  const float* fc1_w   = (const float*)d_in[5];
  const float* fc1_b   = (const float*)d_in[6];
  const float* hm_w    = (const float*)d_in[7];
  const float* hm_b    = (const float*)d_in[8];
  const float* hv_w    = (const float*)d_in[9];
  const float* hv_b    = (const float*)d_in[10];
  const float* sh_w    = (const float*)d_in[11];
  const float* sh_b    = (const float*)d_in[12];
  const float* gamma   = (const float*)d_in[13];

  char* ws = (char*)d_ws;
  // ws: cs 64KB @0 | ylin 16KB @64KB | wscale 8KB @80KB | zq 64MB @1MB | wq 32MB @65MB | h(bf16) 16MB @97MB
  float* cs            = (float*)(ws);
  float* ylin          = (float*)(ws + (64 << 10));
  float* wscale        = (float*)(ws + (80 << 10));
  unsigned char* zq    = (unsigned char*)(ws + (1ull << 20));
  unsigned char* wq    = (unsigned char*)(ws + (65ull << 20));
  unsigned short* h    = (unsigned short*)(ws + (97ull << 20));
  float* out           = (float*)d_out;

  prep_kernel<<<dim3(64),   dim3(256), 0, stream>>>(centers, width, cs);
  zexp_kernel<<<dim3(4096), dim3(256), 0, stream>>>(x, ln_g, ln_b, width, sh_w, sh_b, cs, zq, ylin);
  cvt_kernel <<<dim3(2048), dim3(256), 0, stream>>>(fc1_w, wq, wscale);
  gemm_kernel<<<dim3(256),  dim3(512), 0, stream>>>(zq, wq, wscale, fc1_b, h);
  head_kernel<<<dim3(4096), dim3(256), 0, stream>>>(h, hm_w, hm_b, hv_w, hv_b, ylin, gamma, out);
}